// Round 6
// baseline (26617.902 us; speedup 1.0000x reference)
//
#include <hip/hip_runtime.h>
#include <math.h>

#define NB 128
#define NS 256
#define ND 512
#define NBS (NB*NS)   // 32768
#define KE 544        // 512 x | 10 back | 20 cnn | 1 bias | 1 pad
#define NC 2560       // 2048 cell gates + 512 leap hidden

typedef double d4 __attribute__((ext_vector_type(4)));

// ---------------- device-global scratch ----------------
__device__ double g_A[(size_t)NBS * KE];
__device__ double g_Pre[(size_t)NBS * NC];
__device__ double g_Aproj[(size_t)NBS * 40];
__device__ double g_gum[NS * NB * 2];
__device__ double g_hx[NB * ND];
__device__ double g_c[NB * ND];
__device__ double g_gbuf[NB * NC];
__device__ double g_final[NB * ND];
__device__ float  g_Wext[(size_t)NC * KE];
__device__ float  g_Wstep[(size_t)NC * ND];
__device__ int    g_ok;    // mfma lane-layout probe passed
__device__ int    g_bad;   // g_Pre sample-verify failed

__device__ __forceinline__ double sigd(double x) { return 1.0 / (1.0 + exp(-x)); }

// ---------------- MFMA layout probe (asymmetric, exact-integer check) ----------------
__global__ void mfma_probe() {
    int l = threadIdx.x;                 // 64 threads = 1 wave
    int lr = l & 15, lk = l >> 4;
    double a = 1.0 + lr + 17.0 * lk;     // assumed A[i=lr][k=lk]
    double b = 1.0 + 3.0 * lr + 5.0 * lk; // assumed B[k=lk][j=lr]
    d4 d = {0.0, 0.0, 0.0, 0.0};
    d = __builtin_amdgcn_mfma_f64_16x16x4f64(a, b, d, 0, 0, 0);
    bool okl = true;
#pragma unroll
    for (int r = 0; r < 4; ++r) {
        int i = 4 * lk + r, j = lr;      // assumed D[i][j] at (lane, reg r)
        double e = 0.0;
        for (int k = 0; k < 4; ++k)
            e += (1.0 + i + 17.0 * k) * (1.0 + 3.0 * j + 5.0 * k);
        if (d[r] != e) okl = false;
    }
    unsigned long long vote = __ballot(okl);
    if (l == 0) { g_ok = (vote == 0xFFFFFFFFFFFFFFFFull) ? 1 : 0; g_bad = 0; }
}

// ---------------- init ----------------
__global__ void init_state() {
    int i = blockIdx.x * 256 + threadIdx.x;
    if (i < NB * ND) { g_hx[i] = 0.0; g_c[i] = 0.0; }
}

// ---------------- weight repack ----------------
__global__ __launch_bounds__(256) void build_w(const float* __restrict__ cWih,
                                               const float* __restrict__ cWhh,
                                               const float* __restrict__ W1,
                                               const float* __restrict__ b1) {
    int n = blockIdx.x;                 // 0..2559
    for (int c = threadIdx.x; c < KE; c += 256) {
        float we;
        if (n < 2048) we = (c < 512) ? cWih[(size_t)n * 512 + c] : 0.f;
        else {
            int n2 = n - 2048;
            if      (c < 512)  we = W1[(size_t)n2 * 1054 + 512 + c];
            else if (c < 522)  we = W1[(size_t)n2 * 1054 + 1024 + (c - 512)];
            else if (c < 542)  we = W1[(size_t)n2 * 1054 + 1034 + (c - 522)];
            else if (c == 542) we = b1[n2];
            else               we = 0.f;
        }
        g_Wext[(size_t)n * KE + c] = we;
        if (c < 512)
            g_Wstep[(size_t)n * ND + c] = (n < 2048) ? cWhh[(size_t)n * 512 + c]
                                                     : W1[(size_t)(n - 2048) * 1054 + c];
    }
}

// ---------------- gumbel: JAX partitionable threefry2x32, key (0,42) ----------------
__device__ __forceinline__ unsigned rotl32(unsigned x, int r) { return (x << r) | (x >> (32 - r)); }

__global__ void gumbel_init() {
    unsigned p = blockIdx.x * 256 + threadIdx.x;
    if (p >= 65536u) return;
    unsigned k0 = 0u, k1 = 42u;
    unsigned ks2 = k0 ^ k1 ^ 0x1BD11BDAu;
    unsigned x0 = 0u, x1 = p;
    x0 += k0; x1 += k1;
#define RND(r) { x0 += x1; x1 = rotl32(x1, (r)); x1 ^= x0; }
    RND(13) RND(15) RND(26) RND(6)
    x0 += k1;  x1 += ks2 + 1u;
    RND(17) RND(29) RND(16) RND(24)
    x0 += ks2; x1 += k0 + 2u;
    RND(13) RND(15) RND(26) RND(6)
    x0 += k0;  x1 += k1 + 3u;
    RND(17) RND(29) RND(16) RND(24)
    x0 += k1;  x1 += ks2 + 4u;
    RND(13) RND(15) RND(26) RND(6)
    x0 += ks2; x1 += k0 + 5u;
#undef RND
    unsigned bits = x0 ^ x1;
    float u = __uint_as_float((bits >> 9) | 0x3f800000u) - 1.0f;
    g_gum[p] = log(-log((double)u + 1e-20) + 1e-20);
}

// ---------------- embedding gather+sum ----------------
__global__ __launch_bounds__(128) void embed_sum(const int* __restrict__ seqs,
                                                 const float* __restrict__ emb) {
    int bs = blockIdx.x;
    int tid = threadIdx.x;
    __shared__ int idxs[16];
    if (tid < 16) idxs[tid] = seqs[(size_t)bs * 16 + tid];
    __syncthreads();
    double a0 = 0, a1 = 0, a2 = 0, a3 = 0;
    for (int v = 0; v < 16; ++v) {
        const float4* row = (const float4*)(emb + (size_t)idxs[v] * ND);
        float4 e = row[tid];
        a0 += (double)e.x; a1 += (double)e.y; a2 += (double)e.z; a3 += (double)e.w;
    }
    double* o = g_A + (size_t)bs * KE + tid * 4;
    o[0] = a0; o[1] = a1; o[2] = a2; o[3] = a3;
    if (tid == 0) { g_A[(size_t)bs * KE + 542] = 1.0; g_A[(size_t)bs * KE + 543] = 0.0; }
}

// ---------------- f64 vector GEMM (verified r4 structure; Aproj only) ----------------
__global__ __launch_bounds__(256) void gemm_f64(
    const double* __restrict__ A, int lda,
    const float* __restrict__ W, int ldw,
    double* __restrict__ C, int ldc,
    int M, int N, int K) {
    __shared__ double As[16][66];
    __shared__ double Ws[16][66];
    int m0 = blockIdx.x * 64, n0 = blockIdx.y * 64;
    int tid = threadIdx.x, tx = tid & 15, ty = tid >> 4;
    double acc[4][4] = {};
    for (int k0 = 0; k0 < K; k0 += 16) {
        for (int i = tid; i < 1024; i += 256) {
            int r = i >> 4, c = i & 15;
            As[c][r] = (m0 + r < M && k0 + c < K) ? A[(size_t)(m0 + r) * lda + k0 + c] : 0.0;
            Ws[c][r] = (n0 + r < N && k0 + c < K) ? (double)W[(size_t)(n0 + r) * ldw + k0 + c] : 0.0;
        }
        __syncthreads();
#pragma unroll
        for (int kk = 0; kk < 16; ++kk) {
            double a0 = As[kk][ty*4], a1 = As[kk][ty*4+1], a2 = As[kk][ty*4+2], a3 = As[kk][ty*4+3];
            double w0 = Ws[kk][tx*4], w1 = Ws[kk][tx*4+1], w2 = Ws[kk][tx*4+2], w3 = Ws[kk][tx*4+3];
            acc[0][0] += a0*w0; acc[0][1] += a0*w1; acc[0][2] += a0*w2; acc[0][3] += a0*w3;
            acc[1][0] += a1*w0; acc[1][1] += a1*w1; acc[1][2] += a1*w2; acc[1][3] += a1*w3;
            acc[2][0] += a2*w0; acc[2][1] += a2*w1; acc[2][2] += a2*w2; acc[2][3] += a2*w3;
            acc[3][0] += a3*w0; acc[3][1] += a3*w1; acc[3][2] += a3*w2; acc[3][3] += a3*w3;
        }
        __syncthreads();
    }
#pragma unroll
    for (int i = 0; i < 4; ++i)
#pragma unroll
        for (int j = 0; j < 4; ++j) {
            int m = m0 + ty*4 + i, n = n0 + tx*4 + j;
            if (m < M && n < N) C[(size_t)m * ldc + n] = acc[i][j];
        }
}

// ---------------- big GEMM: g_Pre = g_A[32768,544] @ g_Wext[2560,544]^T (dual path) ----------------
__global__ __launch_bounds__(256) void big_gemm() {
    __shared__ double As[64][33];
    __shared__ double Ws[64][33];
    int tid = threadIdx.x;
    int n0 = blockIdx.x * 64, m0 = blockIdx.y * 64;
    if (g_ok) {
        int lane = tid & 63, wave = tid >> 6;
        int wm = (wave & 1) * 32, wn = (wave >> 1) * 32;
        int lr = lane & 15, lk = lane >> 4;
        d4 a00 = {0,0,0,0}, a01 = {0,0,0,0}, a10 = {0,0,0,0}, a11 = {0,0,0,0};
        for (int k0 = 0; k0 < KE; k0 += 32) {
            for (int i = tid; i < 2048; i += 256) {
                int r = i >> 5, c = i & 31;
                As[r][c] = g_A[(size_t)(m0 + r) * KE + k0 + c];
                Ws[r][c] = (double)g_Wext[(size_t)(n0 + r) * KE + k0 + c];
            }
            __syncthreads();
#pragma unroll
            for (int kk = 0; kk < 8; ++kk) {
                double aLo = As[wm + lr][4*kk + lk];
                double aHi = As[wm + 16 + lr][4*kk + lk];
                double bLo = Ws[wn + lr][4*kk + lk];
                double bHi = Ws[wn + 16 + lr][4*kk + lk];
                a00 = __builtin_amdgcn_mfma_f64_16x16x4f64(aLo, bLo, a00, 0, 0, 0);
                a01 = __builtin_amdgcn_mfma_f64_16x16x4f64(aLo, bHi, a01, 0, 0, 0);
                a10 = __builtin_amdgcn_mfma_f64_16x16x4f64(aHi, bLo, a10, 0, 0, 0);
                a11 = __builtin_amdgcn_mfma_f64_16x16x4f64(aHi, bHi, a11, 0, 0, 0);
            }
            __syncthreads();
        }
        int rb = m0 + wm + 4 * lk;
#pragma unroll
        for (int r = 0; r < 4; ++r) {
            g_Pre[(size_t)(rb + r)      * NC + (n0 + wn + lr)]      = a00[r];
            g_Pre[(size_t)(rb + r)      * NC + (n0 + wn + 16 + lr)] = a01[r];
            g_Pre[(size_t)(rb + 16 + r) * NC + (n0 + wn + lr)]      = a10[r];
            g_Pre[(size_t)(rb + 16 + r) * NC + (n0 + wn + 16 + lr)] = a11[r];
        }
    } else {
        int tx = tid & 15, ty = tid >> 4;
        double acc[4][4] = {};
        for (int k0 = 0; k0 < KE; k0 += 32) {
            for (int i = tid; i < 2048; i += 256) {
                int r = i >> 5, c = i & 31;
                As[r][c] = g_A[(size_t)(m0 + r) * KE + k0 + c];
                Ws[r][c] = (double)g_Wext[(size_t)(n0 + r) * KE + k0 + c];
            }
            __syncthreads();
            for (int kk = 0; kk < 32; ++kk) {
                double a0 = As[ty*4][kk], a1 = As[ty*4+1][kk], a2 = As[ty*4+2][kk], a3 = As[ty*4+3][kk];
                double w0 = Ws[tx*4][kk], w1 = Ws[tx*4+1][kk], w2 = Ws[tx*4+2][kk], w3 = Ws[tx*4+3][kk];
                acc[0][0] += a0*w0; acc[0][1] += a0*w1; acc[0][2] += a0*w2; acc[0][3] += a0*w3;
                acc[1][0] += a1*w0; acc[1][1] += a1*w1; acc[1][2] += a1*w2; acc[1][3] += a1*w3;
                acc[2][0] += a2*w0; acc[2][1] += a2*w1; acc[2][2] += a2*w2; acc[2][3] += a2*w3;
                acc[3][0] += a3*w0; acc[3][1] += a3*w1; acc[3][2] += a3*w2; acc[3][3] += a3*w3;
            }
            __syncthreads();
        }
#pragma unroll
        for (int i = 0; i < 4; ++i)
#pragma unroll
            for (int j = 0; j < 4; ++j)
                g_Pre[(size_t)(m0 + ty*4 + i) * NC + (n0 + tx*4 + j)] = acc[i][j];
    }
}

// ---------------- sample-verify g_Pre vs direct dot ----------------
__global__ void verify_pre() {
    int s = blockIdx.x * 256 + threadIdx.x;    // 8192 samples
    unsigned m = ((unsigned)s * 2654435761u) & 32767u;
    unsigned n = ((unsigned)s * 40503u + 7u) % 2560u;
    double dot = 0.0;
    const double* ar = g_A + (size_t)m * KE;
    const float*  wr = g_Wext + (size_t)n * KE;
    for (int c = 0; c < KE; ++c) dot += ar[c] * (double)wr[c];
    double got = g_Pre[(size_t)m * NC + n];
    if (fabs(got - dot) > 1e-9 * fmax(1.0, fabs(dot))) atomicOr(&g_bad, 1);
}

// ---------------- full vector recompute of g_Pre (runs only if ok && bad) ----------------
__global__ __launch_bounds__(256) void big_fix() {
    if (!(g_ok && g_bad)) return;
    __shared__ double As[64][33];
    __shared__ double Ws[64][33];
    int tid = threadIdx.x, tx = tid & 15, ty = tid >> 4;
    for (int tile = blockIdx.x; tile < (NC/64) * (NBS/64); tile += gridDim.x) {
        int n0 = (tile % (NC/64)) * 64, m0 = (tile / (NC/64)) * 64;
        double acc[4][4] = {};
        for (int k0 = 0; k0 < KE; k0 += 32) {
            for (int i = tid; i < 2048; i += 256) {
                int r = i >> 5, c = i & 31;
                As[r][c] = g_A[(size_t)(m0 + r) * KE + k0 + c];
                Ws[r][c] = (double)g_Wext[(size_t)(n0 + r) * KE + k0 + c];
            }
            __syncthreads();
            for (int kk = 0; kk < 32; ++kk) {
                double a0 = As[ty*4][kk], a1 = As[ty*4+1][kk], a2 = As[ty*4+2][kk], a3 = As[ty*4+3][kk];
                double w0 = Ws[tx*4][kk], w1 = Ws[tx*4+1][kk], w2 = Ws[tx*4+2][kk], w3 = Ws[tx*4+3][kk];
                acc[0][0] += a0*w0; acc[0][1] += a0*w1; acc[0][2] += a0*w2; acc[0][3] += a0*w3;
                acc[1][0] += a1*w0; acc[1][1] += a1*w1; acc[1][2] += a1*w2; acc[1][3] += a1*w3;
                acc[2][0] += a2*w0; acc[2][1] += a2*w1; acc[2][2] += a2*w2; acc[2][3] += a2*w3;
                acc[3][0] += a3*w0; acc[3][1] += a3*w1; acc[3][2] += a3*w2; acc[3][3] += a3*w3;
            }
            __syncthreads();
        }
#pragma unroll
        for (int i = 0; i < 4; ++i)
#pragma unroll
            for (int j = 0; j < 4; ++j)
                g_Pre[(size_t)(m0 + ty*4 + i) * NC + (n0 + tx*4 + j)] = acc[i][j];
        __syncthreads();
    }
}

// ---------------- reverse LSTM (hidden=10) ----------------
__global__ __launch_bounds__(64) void rev_lstm(const float* __restrict__ Whh) {
    int b = blockIdx.x;
    int tid = threadIdx.x;
    __shared__ double h[10], cc[10], g[40], wsh[400];
    for (int i = tid; i < 400; i += 64) wsh[i] = (double)Whh[i];
    if (tid < 10) { h[tid] = 0.0; cc[tid] = 0.0; }
    __syncthreads();
    for (int s = NS - 1; s >= 0; --s) {
        if (tid < 40) {
            double acc = g_Aproj[((size_t)b * NS + s) * 40 + tid];
#pragma unroll
            for (int k = 0; k < 10; ++k) acc += h[k] * wsh[tid * 10 + k];
            g[tid] = acc;
        }
        __syncthreads();
        if (tid < 10) {
            double gi = g[tid], gf = g[10 + tid], gg = g[20 + tid], go = g[30 + tid];
            double cn = sigd(gf) * cc[tid] + sigd(gi) * tanh(gg);
            cc[tid] = cn;
            double hn = sigd(go) * tanh(cn);
            h[tid] = hn;
            g_A[((size_t)b * NS + s) * KE + 512 + tid] = hn;
        }
        __syncthreads();
    }
}

// ---------------- conv1d(512->20, k=3, pad=1) + relu ----------------
__global__ __launch_bounds__(256) void conv_relu(const float* __restrict__ w) {
    int b = blockIdx.x, s0 = blockIdx.y * 8;
    int tid = threadIdx.x, grp = tid >> 5, lane = tid & 31;
    __shared__ double xs[10][ND];
    for (int i = tid; i < 10 * ND; i += 256) {
        int r = i >> 9, d = i & (ND - 1);
        int s = s0 - 1 + r;
        xs[r][d] = (s >= 0 && s < NS) ? g_A[((size_t)b * NS + s) * KE + d] : 0.0;
    }
    __syncthreads();
    int s = s0 + grp;
    for (int o = 0; o < 20; ++o) {
        const float* wo = w + (size_t)o * 1536;
        double acc = 0.0;
        for (int d = lane; d < ND; d += 32) {
            acc += xs[grp][d]     * (double)wo[d*3]
                 + xs[grp + 1][d] * (double)wo[d*3 + 1]
                 + xs[grp + 2][d] * (double)wo[d*3 + 2];
        }
        for (int m = 16; m > 0; m >>= 1) acc += __shfl_xor(acc, m, 32);
        if (lane == 0)
            g_A[((size_t)b * NS + s) * KE + 522 + o] = acc > 0.0 ? acc : 0.0;
    }
}

// ---------------- per-step GEMM (dual path): g_gbuf = hx @ Wstep^T + g_Pre[:,t,:] ----------------
__global__ __launch_bounds__(256) void step_gemm2(int t) {
    __shared__ double As[32][33];
    __shared__ double Ws[64][33];
    int tid = threadIdx.x;
    int m0 = blockIdx.x * 32, n0 = blockIdx.y * 64;
    int use_mfma = g_ok && !g_bad;
    if (use_mfma) {
        int lane = tid & 63, wave = tid >> 6;
        int wm = (wave & 1) * 16, wn = (wave >> 1) * 32;
        int lr = lane & 15, lk = lane >> 4;
        int rb = m0 + wm + 4 * lk;
        int cb0 = n0 + wn + lr, cb1 = n0 + wn + 16 + lr;
        double pre0[4], pre1[4];
#pragma unroll
        for (int r = 0; r < 4; ++r) {
            pre0[r] = g_Pre[((size_t)(rb + r) * NS + t) * NC + cb0];
            pre1[r] = g_Pre[((size_t)(rb + r) * NS + t) * NC + cb1];
        }
        d4 acc0 = {0,0,0,0}, acc1 = {0,0,0,0};
        for (int k0 = 0; k0 < ND; k0 += 32) {
            for (int i = tid; i < 1024; i += 256) {
                int r = i >> 5, c = i & 31;
                As[r][c] = g_hx[(size_t)(m0 + r) * ND + k0 + c];
            }
            for (int i = tid; i < 2048; i += 256) {
                int r = i >> 5, c = i & 31;
                Ws[r][c] = (double)g_Wstep[(size_t)(n0 + r) * ND + k0 + c];
            }
            __syncthreads();
#pragma unroll
            for (int kk = 0; kk < 8; ++kk) {
                double av  = As[wm + lr][4*kk + lk];
                double bLo = Ws[wn + lr][4*kk + lk];
                double bHi = Ws[wn + 16 + lr][4*kk + lk];
                acc0 = __builtin_amdgcn_mfma_f64_16x16x4f64(av, bLo, acc0, 0, 0, 0);
                acc1 = __builtin_amdgcn_mfma_f64_16x16x4f64(av, bHi, acc1, 0, 0, 0);
            }
            __syncthreads();
        }
#pragma unroll
        for (int r = 0; r < 4; ++r) {
            g_gbuf[(size_t)(rb + r) * NC + cb0] = acc0[r] + pre0[r];
            g_gbuf[(size_t)(rb + r) * NC + cb1] = acc1[r] + pre1[r];
        }
    } else {
        int tx = tid & 15, ty = tid >> 4;
        double acc[2][4] = {};
        for (int k0 = 0; k0 < ND; k0 += 32) {
            for (int i = tid; i < 1024; i += 256) {
                int r = i >> 5, c = i & 31;
                As[r][c] = g_hx[(size_t)(m0 + r) * ND + k0 + c];
            }
            for (int i = tid; i < 2048; i += 256) {
                int r = i >> 5, c = i & 31;
                Ws[r][c] = (double)g_Wstep[(size_t)(n0 + r) * ND + k0 + c];
            }
            __syncthreads();
            for (int kk = 0; kk < 32; ++kk) {
                double a0 = As[ty*2][kk], a1 = As[ty*2+1][kk];
                double w0 = Ws[tx*4][kk], w1 = Ws[tx*4+1][kk], w2 = Ws[tx*4+2][kk], w3 = Ws[tx*4+3][kk];
                acc[0][0] += a0*w0; acc[0][1] += a0*w1; acc[0][2] += a0*w2; acc[0][3] += a0*w3;
                acc[1][0] += a1*w0; acc[1][1] += a1*w1; acc[1][2] += a1*w2; acc[1][3] += a1*w3;
            }
            __syncthreads();
        }
#pragma unroll
        for (int i = 0; i < 2; ++i)
#pragma unroll
            for (int j = 0; j < 4; ++j) {
                int m = m0 + ty*2 + i, n = n0 + tx*4 + j;
                g_gbuf[(size_t)m * NC + n] = acc[i][j] + g_Pre[((size_t)m * NS + t) * NC + n];
            }
    }
}

// ---------------- per-step elementwise ----------------
__global__ __launch_bounds__(256) void step_update(
    const float* __restrict__ W2, const float* __restrict__ b2,
    const int* __restrict__ lengths, int t) {
    int b = blockIdx.x, tid = threadIdx.x;
    const double* gb = g_gbuf + (size_t)b * NC;
    __shared__ double red[256][2];
    __shared__ double skipsh[2];
    double p0 = 0.0, p1 = 0.0;
    for (int j = tid; j < ND; j += 256) {
        double h = gb[2048 + j];
        h = h > 0.0 ? h : 0.0;
        p0 += h * (double)W2[j];
        p1 += h * (double)W2[ND + j];
    }
    red[tid][0] = p0; red[tid][1] = p1;
    __syncthreads();
    for (int s = 128; s > 0; s >>= 1) {
        if (tid < s) { red[tid][0] += red[tid + s][0]; red[tid][1] += red[tid + s][1]; }
        __syncthreads();
    }
    if (tid == 0) {
        double l0 = red[0][0] + (double)b2[0], l1 = red[0][1] + (double)b2[1];
        double mx = fmax(l0, l1);
        double sh0 = l0 - mx, sh1 = l1 - mx;
        double lsum = log(exp(sh0) + exp(sh1));
        double y0 = (sh0 - lsum) - g_gum[(size_t)t * (NB * 2) + b * 2 + 0];
        double y1 = (sh1 - lsum) - g_gum[(size_t)t * (NB * 2) + b * 2 + 1];
        double xx0 = y0 / 1e-5, xx1 = y1 / 1e-5;
        double mm = fmax(xx0, xx1);
        double e0 = exp(xx0 - mm), e1 = exp(xx1 - mm);
        double inv = 1.0 / (e0 + e1);
        skipsh[0] = e0 * inv; skipsh[1] = e1 * inv;
    }
    __syncthreads();
    double s0 = skipsh[0], s1 = skipsh[1];
    bool isFinal = (t == lengths[b] - 1);
    for (int j = tid; j < ND; j += 256) {
        double gi = gb[j], gf = gb[ND + j], gg = gb[2*ND + j], go = gb[3*ND + j];
        size_t ix = (size_t)b * ND + j;
        double cn = sigd(gf) * g_c[ix] + sigd(gi) * tanh(gg);
        double shx = sigd(go) * tanh(cn);
        double hn = g_hx[ix] * s1 + shx * s0;
        g_c[ix] = cn;
        g_hx[ix] = hn;
        if (isFinal) g_final[ix] = hn;
    }
}

// ---------------- final projection ----------------
__global__ __launch_bounds__(256) void final_out(const float* __restrict__ Wo,
                                                 const float* __restrict__ bo,
                                                 float* __restrict__ out) {
    int tid = threadIdx.x;
    int b = tid >> 1, k = tid & 1;
    double acc = 0.0;
    const double* f = g_final + (size_t)b * ND;
    const float* w = Wo + (size_t)k * ND;
    for (int d = 0; d < ND; ++d) acc += f[d] * (double)w[d];
    out[b * 2 + k] = (float)(acc + (double)bo[k]);
}

// ---------------- host launcher ----------------
extern "C" void kernel_launch(void* const* d_in, const int* in_sizes, int n_in,
                              void* d_out, int out_size, void* d_ws, size_t ws_size,
                              hipStream_t stream) {
    (void)in_sizes; (void)n_in; (void)d_ws; (void)ws_size; (void)out_size;
    const int*   seqs    = (const int*)d_in[0];
    const int*   lengths = (const int*)d_in[2];
    const float* emb     = (const float*)d_in[5];
    const float* revWih  = (const float*)d_in[6];
    const float* revWhh  = (const float*)d_in[7];
    const float* convw   = (const float*)d_in[8];
    const float* W1      = (const float*)d_in[9];
    const float* b1      = (const float*)d_in[10];
    const float* W2      = (const float*)d_in[11];
    const float* b2      = (const float*)d_in[12];
    const float* cWih    = (const float*)d_in[13];
    const float* cWhh    = (const float*)d_in[14];
    const float* Wo      = (const float*)d_in[15];
    const float* bo      = (const float*)d_in[16];
    float* out = (float*)d_out;

    double *A_p = nullptr, *Ap_p = nullptr;
    hipGetSymbolAddress((void**)&A_p,  HIP_SYMBOL(g_A));
    hipGetSymbolAddress((void**)&Ap_p, HIP_SYMBOL(g_Aproj));

    mfma_probe<<<1, 64, 0, stream>>>();
    build_w<<<NC, 256, 0, stream>>>(cWih, cWhh, W1, b1);
    init_state<<<256, 256, 0, stream>>>();
    gumbel_init<<<256, 256, 0, stream>>>();
    embed_sum<<<NBS, 128, 0, stream>>>(seqs, emb);

    gemm_f64<<<dim3(NBS / 64, 1), 256, 0, stream>>>(A_p, KE, revWih, ND, Ap_p, 40,
                                                    NBS, 40, ND);
    rev_lstm<<<NB, 64, 0, stream>>>(revWhh);
    conv_relu<<<dim3(NB, NS / 8), 256, 0, stream>>>(convw);

    big_gemm<<<dim3(NC / 64, NBS / 64), 256, 0, stream>>>();
    verify_pre<<<32, 256, 0, stream>>>();
    big_fix<<<2048, 256, 0, stream>>>();

    for (int t = 0; t < NS; ++t) {
        step_gemm2<<<dim3(4, 40), 256, 0, stream>>>(t);
        step_update<<<NB, 256, 0, stream>>>(W2, b2, lengths, t);
    }
    final_out<<<1, 256, 0, stream>>>(Wo, bo, out);
}

// Round 7
// 12200.413 us; speedup vs baseline: 2.1817x; 2.1817x over previous
//
#include <hip/hip_runtime.h>
#include <math.h>

#define NB 128
#define NS 256
#define ND 512
#define NBS (NB*NS)   // 32768
#define KE 544        // 512 x | 10 back | 20 cnn | 1 bias | 1 pad
#define NC 2560       // 2048 cell gates + 512 leap hidden

typedef unsigned short u16;
typedef __attribute__((ext_vector_type(8))) short s8v;   // 8 bf16 (4 VGPRs)
typedef __attribute__((ext_vector_type(4))) float f4v;   // 4 f32 acc

static constexpr size_t PSA  = (size_t)NBS * KE;   // g_Ab plane stride
static constexpr size_t PSWE = (size_t)NC  * KE;
static constexpr size_t PSWS = (size_t)NC  * ND;
static constexpr size_t PSH  = (size_t)NB  * ND;

// ---------------- device-global scratch ----------------
__device__ double g_A[(size_t)NBS * KE];      // f64 extended activation (fallback + verify truth)
__device__ u16    g_Ab[3 * PSA];              // bf16x3 planes of g_A
__device__ float  g_Pre[(size_t)NBS * NC];    // all input-side preactivations (f32)
__device__ double g_Aproj[(size_t)NBS * 40];
__device__ double g_gum[NS * NB * 2];
__device__ double g_hx[NB * ND];
__device__ u16    g_hxb[3 * NB * ND];         // bf16x3 planes of hx
__device__ double g_c[NB * ND];
__device__ double g_gbuf[NB * NC];
__device__ double g_final[NB * ND];
__device__ float  g_Wext[PSWE];
__device__ u16    g_Wextb[3 * PSWE];
__device__ float  g_Wstep[PSWS];
__device__ u16    g_Wstepb[3 * PSWS];
__device__ int    g_ok, g_bad, g_badstep;

__device__ __forceinline__ double sigd(double x) { return 1.0 / (1.0 + exp(-x)); }
__device__ __forceinline__ u16 f2bf(float f) {
    unsigned u = __float_as_uint(f);
    return (u16)((u + 0x7FFFu + ((u >> 16) & 1u)) >> 16);   // RNE
}
__device__ __forceinline__ float bf2f(u16 b) { return __uint_as_float(((unsigned)b) << 16); }
__device__ __forceinline__ void decomp3(float f, u16& b0, u16& b1, u16& b2) {
    b0 = f2bf(f); float r1 = f - bf2f(b0);
    b1 = f2bf(r1); float r2 = r1 - bf2f(b1);
    b2 = f2bf(r2);
}

#define MFMA_BF16 __builtin_amdgcn_mfma_f32_16x16x32_bf16
// principal into AP, 5 correction terms into AC (bf16x3, drop i+j>=3)
#define STEP6(AP,AC,A0,A1,A2,B0,B1,B2) \
    AP = MFMA_BF16(A0, B0, AP, 0, 0, 0); \
    AC = MFMA_BF16(A0, B1, AC, 0, 0, 0); \
    AC = MFMA_BF16(A1, B0, AC, 0, 0, 0); \
    AC = MFMA_BF16(A0, B2, AC, 0, 0, 0); \
    AC = MFMA_BF16(A1, B1, AC, 0, 0, 0); \
    AC = MFMA_BF16(A2, B0, AC, 0, 0, 0);

// ---------------- bf16 MFMA layout probe (asymmetric, exact-integer) ----------------
__global__ void probe_bf16() {
    int l = threadIdx.x, lr = l & 15, lk = l >> 4;
    s8v a, b;
#pragma unroll
    for (int e = 0; e < 8; ++e) {
        int k = 8 * lk + e;
        a[e] = (short)f2bf((float)(((3 * lr + 7 * k) % 13) + 1));   // A[i=lr][k]
        b[e] = (short)f2bf((float)(((5 * k + 11 * lr) % 17) + 1));  // B[k][j=lr]
    }
    f4v d = {0.f, 0.f, 0.f, 0.f};
    d = MFMA_BF16(a, b, d, 0, 0, 0);
    bool okl = true;
#pragma unroll
    for (int r = 0; r < 4; ++r) {
        int row = 4 * lk + r, col = lr;
        int e = 0;
        for (int k = 0; k < 32; ++k)
            e += (((3 * row + 7 * k) % 13) + 1) * (((5 * k + 11 * col) % 17) + 1);
        if (d[r] != (float)e) okl = false;
    }
    unsigned long long vote = __ballot(okl);
    if (l == 0) { g_ok = (vote == 0xFFFFFFFFFFFFFFFFull) ? 1 : 0; g_bad = 0; g_badstep = 0; }
}

// ---------------- init ----------------
__global__ void init_state() {
    int i = blockIdx.x * 256 + threadIdx.x;
    if (i < NB * ND) {
        g_hx[i] = 0.0; g_c[i] = 0.0;
        g_hxb[i] = 0; g_hxb[PSH + i] = 0; g_hxb[2 * PSH + i] = 0;
    }
}

// ---------------- weight repack + bf16x3 decomposition ----------------
__global__ __launch_bounds__(256) void build_w(const float* __restrict__ cWih,
                                               const float* __restrict__ cWhh,
                                               const float* __restrict__ W1,
                                               const float* __restrict__ b1) {
    int n = blockIdx.x;                 // 0..2559
    for (int c = threadIdx.x; c < KE; c += 256) {
        float we;
        if (n < 2048) we = (c < 512) ? cWih[(size_t)n * 512 + c] : 0.f;
        else {
            int n2 = n - 2048;
            if      (c < 512)  we = W1[(size_t)n2 * 1054 + 512 + c];
            else if (c < 522)  we = W1[(size_t)n2 * 1054 + 1024 + (c - 512)];
            else if (c < 542)  we = W1[(size_t)n2 * 1054 + 1034 + (c - 522)];
            else if (c == 542) we = b1[n2];
            else               we = 0.f;
        }
        size_t ix = (size_t)n * KE + c;
        g_Wext[ix] = we;
        u16 b0, b1_, b2; decomp3(we, b0, b1_, b2);
        g_Wextb[ix] = b0; g_Wextb[PSWE + ix] = b1_; g_Wextb[2 * PSWE + ix] = b2;
        if (c < 512) {
            float ws = (n < 2048) ? cWhh[(size_t)n * 512 + c]
                                  : W1[(size_t)(n - 2048) * 1054 + c];
            size_t ix2 = (size_t)n * ND + c;
            g_Wstep[ix2] = ws;
            decomp3(ws, b0, b1_, b2);
            g_Wstepb[ix2] = b0; g_Wstepb[PSWS + ix2] = b1_; g_Wstepb[2 * PSWS + ix2] = b2;
        }
    }
}

// ---------------- gumbel: JAX partitionable threefry2x32, key (0,42) ----------------
__device__ __forceinline__ unsigned rotl32(unsigned x, int r) { return (x << r) | (x >> (32 - r)); }

__global__ void gumbel_init() {
    unsigned p = blockIdx.x * 256 + threadIdx.x;
    if (p >= 65536u) return;
    unsigned k0 = 0u, k1 = 42u;
    unsigned ks2 = k0 ^ k1 ^ 0x1BD11BDAu;
    unsigned x0 = 0u, x1 = p;
    x0 += k0; x1 += k1;
#define RND(r) { x0 += x1; x1 = rotl32(x1, (r)); x1 ^= x0; }
    RND(13) RND(15) RND(26) RND(6)
    x0 += k1;  x1 += ks2 + 1u;
    RND(17) RND(29) RND(16) RND(24)
    x0 += ks2; x1 += k0 + 2u;
    RND(13) RND(15) RND(26) RND(6)
    x0 += k0;  x1 += k1 + 3u;
    RND(17) RND(29) RND(16) RND(24)
    x0 += k1;  x1 += ks2 + 4u;
    RND(13) RND(15) RND(26) RND(6)
    x0 += ks2; x1 += k0 + 5u;
#undef RND
    unsigned bits = x0 ^ x1;
    float u = __uint_as_float((bits >> 9) | 0x3f800000u) - 1.0f;
    g_gum[p] = log(-log((double)u + 1e-20) + 1e-20);
}

// ---------------- embedding gather+sum ----------------
__global__ __launch_bounds__(128) void embed_sum(const int* __restrict__ seqs,
                                                 const float* __restrict__ emb) {
    int bs = blockIdx.x;
    int tid = threadIdx.x;
    __shared__ int idxs[16];
    if (tid < 16) idxs[tid] = seqs[(size_t)bs * 16 + tid];
    __syncthreads();
    double a0 = 0, a1 = 0, a2 = 0, a3 = 0;
    for (int v = 0; v < 16; ++v) {
        const float4* row = (const float4*)(emb + (size_t)idxs[v] * ND);
        float4 e = row[tid];
        a0 += (double)e.x; a1 += (double)e.y; a2 += (double)e.z; a3 += (double)e.w;
    }
    double* o = g_A + (size_t)bs * KE + tid * 4;
    o[0] = a0; o[1] = a1; o[2] = a2; o[3] = a3;
    if (tid == 0) { g_A[(size_t)bs * KE + 542] = 1.0; g_A[(size_t)bs * KE + 543] = 0.0; }
}

// ---------------- decompose g_A -> bf16x3 planes (after rev_lstm & conv fill cols 512..541) ----------------
__global__ void decomp_A() {
    for (size_t i = (size_t)blockIdx.x * 256 + threadIdx.x; i < PSA; i += (size_t)gridDim.x * 256) {
        float f = (float)g_A[i];
        u16 b0, b1, b2; decomp3(f, b0, b1, b2);
        g_Ab[i] = b0; g_Ab[PSA + i] = b1; g_Ab[2 * PSA + i] = b2;
    }
}

// ---------------- f64 vector GEMM (verified r4 structure; Aproj only) ----------------
__global__ __launch_bounds__(256) void gemm_f64(
    const double* __restrict__ A, int lda,
    const float* __restrict__ W, int ldw,
    double* __restrict__ C, int ldc,
    int M, int N, int K) {
    __shared__ double As[16][66];
    __shared__ double Ws[16][66];
    int m0 = blockIdx.x * 64, n0 = blockIdx.y * 64;
    int tid = threadIdx.x, tx = tid & 15, ty = tid >> 4;
    double acc[4][4] = {};
    for (int k0 = 0; k0 < K; k0 += 16) {
        for (int i = tid; i < 1024; i += 256) {
            int r = i >> 4, c = i & 15;
            As[c][r] = (m0 + r < M && k0 + c < K) ? A[(size_t)(m0 + r) * lda + k0 + c] : 0.0;
            Ws[c][r] = (n0 + r < N && k0 + c < K) ? (double)W[(size_t)(n0 + r) * ldw + k0 + c] : 0.0;
        }
        __syncthreads();
#pragma unroll
        for (int kk = 0; kk < 16; ++kk) {
            double a0 = As[kk][ty*4], a1 = As[kk][ty*4+1], a2 = As[kk][ty*4+2], a3 = As[kk][ty*4+3];
            double w0 = Ws[kk][tx*4], w1 = Ws[kk][tx*4+1], w2 = Ws[kk][tx*4+2], w3 = Ws[kk][tx*4+3];
            acc[0][0] += a0*w0; acc[0][1] += a0*w1; acc[0][2] += a0*w2; acc[0][3] += a0*w3;
            acc[1][0] += a1*w0; acc[1][1] += a1*w1; acc[1][2] += a1*w2; acc[1][3] += a1*w3;
            acc[2][0] += a2*w0; acc[2][1] += a2*w1; acc[2][2] += a2*w2; acc[2][3] += a2*w3;
            acc[3][0] += a3*w0; acc[3][1] += a3*w1; acc[3][2] += a3*w2; acc[3][3] += a3*w3;
        }
        __syncthreads();
    }
#pragma unroll
    for (int i = 0; i < 4; ++i)
#pragma unroll
        for (int j = 0; j < 4; ++j) {
            int m = m0 + ty*4 + i, n = n0 + tx*4 + j;
            if (m < M && n < N) C[(size_t)m * ldc + n] = acc[i][j];
        }
}

// ---------------- reverse LSTM (hidden=10) ----------------
__global__ __launch_bounds__(64) void rev_lstm(const float* __restrict__ Whh) {
    int b = blockIdx.x;
    int tid = threadIdx.x;
    __shared__ double h[10], cc[10], g[40], wsh[400];
    for (int i = tid; i < 400; i += 64) wsh[i] = (double)Whh[i];
    if (tid < 10) { h[tid] = 0.0; cc[tid] = 0.0; }
    __syncthreads();
    for (int s = NS - 1; s >= 0; --s) {
        if (tid < 40) {
            double acc = g_Aproj[((size_t)b * NS + s) * 40 + tid];
#pragma unroll
            for (int k = 0; k < 10; ++k) acc += h[k] * wsh[tid * 10 + k];
            g[tid] = acc;
        }
        __syncthreads();
        if (tid < 10) {
            double gi = g[tid], gf = g[10 + tid], gg = g[20 + tid], go = g[30 + tid];
            double cn = sigd(gf) * cc[tid] + sigd(gi) * tanh(gg);
            cc[tid] = cn;
            double hn = sigd(go) * tanh(cn);
            h[tid] = hn;
            g_A[((size_t)b * NS + s) * KE + 512 + tid] = hn;
        }
        __syncthreads();
    }
}

// ---------------- conv1d(512->20, k=3, pad=1) + relu ----------------
__global__ __launch_bounds__(256) void conv_relu(const float* __restrict__ w) {
    int b = blockIdx.x, s0 = blockIdx.y * 8;
    int tid = threadIdx.x, grp = tid >> 5, lane = tid & 31;
    __shared__ double xs[10][ND];
    for (int i = tid; i < 10 * ND; i += 256) {
        int r = i >> 9, d = i & (ND - 1);
        int s = s0 - 1 + r;
        xs[r][d] = (s >= 0 && s < NS) ? g_A[((size_t)b * NS + s) * KE + d] : 0.0;
    }
    __syncthreads();
    int s = s0 + grp;
    for (int o = 0; o < 20; ++o) {
        const float* wo = w + (size_t)o * 1536;
        double acc = 0.0;
        for (int d = lane; d < ND; d += 32) {
            acc += xs[grp][d]     * (double)wo[d*3]
                 + xs[grp + 1][d] * (double)wo[d*3 + 1]
                 + xs[grp + 2][d] * (double)wo[d*3 + 2];
        }
        for (int m = 16; m > 0; m >>= 1) acc += __shfl_xor(acc, m, 32);
        if (lane == 0)
            g_A[((size_t)b * NS + s) * KE + 522 + o] = acc > 0.0 ? acc : 0.0;
    }
}

// ---------------- big GEMM: g_Pre = g_A[32768,544] @ g_Wext[2560,544]^T (bf16x3 MFMA | f64 vector) ----------------
__global__ __launch_bounds__(256) void big_gemm() {
    __shared__ __align__(16) unsigned char shm[36864];
    int tid = threadIdx.x;
    int n0 = blockIdx.x * 64, m0 = blockIdx.y * 64;
    if (g_ok) {
        u16* usA = (u16*)shm;            // [3][64][48], cols 0..31 used
        u16* usB = usA + 9216;
        int lane = tid & 63, wave = tid >> 6;
        int wm = (wave & 1) * 32, wn = (wave >> 1) * 32;
        int lr = lane & 15, lk = lane >> 4;
        f4v z = {0.f,0.f,0.f,0.f};
        f4v aP00=z,aP01=z,aP10=z,aP11=z, aC00=z,aC01=z,aC10=z,aC11=z;
        for (int k0 = 0; k0 < KE; k0 += 32) {
            for (int i = tid; i < 1536; i += 256) {
                if (i < 768) {
                    int p = i >> 8, rem = i & 255, r = rem >> 2, sg = rem & 3;
                    *(uint4*)(void*)(usA + p*3072 + r*48 + sg*8) =
                        *(const uint4*)(const void*)(g_Ab + (size_t)p*PSA + (size_t)(m0+r)*KE + k0 + sg*8);
                } else {
                    int j = i - 768;
                    int p = j >> 8, rem = j & 255, r = rem >> 2, sg = rem & 3;
                    *(uint4*)(void*)(usB + p*3072 + r*48 + sg*8) =
                        *(const uint4*)(const void*)(g_Wextb + (size_t)p*PSWE + (size_t)(n0+r)*KE + k0 + sg*8);
                }
            }
            __syncthreads();
            const u16* pa = usA + (wm + lr) * 48 + 8 * lk;
            const u16* pb = usB + (wn + lr) * 48 + 8 * lk;
            s8v a0_0 = *(const s8v*)(const void*)(pa);
            s8v a0_1 = *(const s8v*)(const void*)(pa + 768);
            s8v a1_0 = *(const s8v*)(const void*)(pa + 3072);
            s8v a1_1 = *(const s8v*)(const void*)(pa + 3840);
            s8v a2_0 = *(const s8v*)(const void*)(pa + 6144);
            s8v a2_1 = *(const s8v*)(const void*)(pa + 6912);
            s8v b0_0 = *(const s8v*)(const void*)(pb);
            s8v b0_1 = *(const s8v*)(const void*)(pb + 768);
            s8v b1_0 = *(const s8v*)(const void*)(pb + 3072);
            s8v b1_1 = *(const s8v*)(const void*)(pb + 3840);
            s8v b2_0 = *(const s8v*)(const void*)(pb + 6144);
            s8v b2_1 = *(const s8v*)(const void*)(pb + 6912);
            STEP6(aP00, aC00, a0_0, a1_0, a2_0, b0_0, b1_0, b2_0)
            STEP6(aP01, aC01, a0_0, a1_0, a2_0, b0_1, b1_1, b2_1)
            STEP6(aP10, aC10, a0_1, a1_1, a2_1, b0_0, b1_0, b2_0)
            STEP6(aP11, aC11, a0_1, a1_1, a2_1, b0_1, b1_1, b2_1)
            __syncthreads();
        }
        int rb = m0 + wm + 4 * lk, cb0 = n0 + wn + lr, cb1 = cb0 + 16;
#pragma unroll
        for (int r = 0; r < 4; ++r) {
            g_Pre[(size_t)(rb + r)      * NC + cb0] = aP00[r] + aC00[r];
            g_Pre[(size_t)(rb + r)      * NC + cb1] = aP01[r] + aC01[r];
            g_Pre[(size_t)(rb + 16 + r) * NC + cb0] = aP10[r] + aC10[r];
            g_Pre[(size_t)(rb + 16 + r) * NC + cb1] = aP11[r] + aC11[r];
        }
    } else {
        double* Asd = (double*)shm;          // [64][33]
        double* Wsd = Asd + 64 * 33;
        int tx = tid & 15, ty = tid >> 4;
        double acc[4][4] = {};
        for (int k0 = 0; k0 < KE; k0 += 32) {
            for (int i = tid; i < 2048; i += 256) {
                int r = i >> 5, c = i & 31;
                Asd[r * 33 + c] = g_A[(size_t)(m0 + r) * KE + k0 + c];
                Wsd[r * 33 + c] = (double)g_Wext[(size_t)(n0 + r) * KE + k0 + c];
            }
            __syncthreads();
            for (int kk = 0; kk < 32; ++kk) {
                double a0 = Asd[(ty*4)*33+kk], a1 = Asd[(ty*4+1)*33+kk], a2 = Asd[(ty*4+2)*33+kk], a3 = Asd[(ty*4+3)*33+kk];
                double w0 = Wsd[(tx*4)*33+kk], w1 = Wsd[(tx*4+1)*33+kk], w2 = Wsd[(tx*4+2)*33+kk], w3 = Wsd[(tx*4+3)*33+kk];
                acc[0][0] += a0*w0; acc[0][1] += a0*w1; acc[0][2] += a0*w2; acc[0][3] += a0*w3;
                acc[1][0] += a1*w0; acc[1][1] += a1*w1; acc[1][2] += a1*w2; acc[1][3] += a1*w3;
                acc[2][0] += a2*w0; acc[2][1] += a2*w1; acc[2][2] += a2*w2; acc[2][3] += a2*w3;
                acc[3][0] += a3*w0; acc[3][1] += a3*w1; acc[3][2] += a3*w2; acc[3][3] += a3*w3;
            }
            __syncthreads();
        }
#pragma unroll
        for (int i = 0; i < 4; ++i)
#pragma unroll
            for (int j = 0; j < 4; ++j)
                g_Pre[(size_t)(m0 + ty*4 + i) * NC + (n0 + tx*4 + j)] = (float)acc[i][j];
    }
}

// ---------------- sample-verify g_Pre vs f64 dot ----------------
__global__ void verify_pre() {
    int s = blockIdx.x * 256 + threadIdx.x;    // 8192 samples
    unsigned m = ((unsigned)s * 2654435761u) & 32767u;
    unsigned n = ((unsigned)s * 40503u + 7u) % 2560u;
    double dot = 0.0;
    const double* ar = g_A + (size_t)m * KE;
    const float*  wr = g_Wext + (size_t)n * KE;
    for (int c = 0; c < KE; ++c) dot += ar[c] * (double)wr[c];
    double got = (double)g_Pre[(size_t)m * NC + n];
    if (fabs(got - dot) > 1e-4 * (1.0 + fabs(dot))) atomicOr(&g_bad, 1);
}

// ---------------- full vector recompute of g_Pre (only if ok && bad) ----------------
__global__ __launch_bounds__(256) void big_fix() {
    if (!(g_ok && g_bad)) return;
    __shared__ double As[64][33];
    __shared__ double Ws[64][33];
    int tid = threadIdx.x, tx = tid & 15, ty = tid >> 4;
    for (int tile = blockIdx.x; tile < (NC/64) * (NBS/64); tile += gridDim.x) {
        int n0 = (tile % (NC/64)) * 64, m0 = (tile / (NC/64)) * 64;
        double acc[4][4] = {};
        for (int k0 = 0; k0 < KE; k0 += 32) {
            for (int i = tid; i < 2048; i += 256) {
                int r = i >> 5, c = i & 31;
                As[r][c] = g_A[(size_t)(m0 + r) * KE + k0 + c];
                Ws[r][c] = (double)g_Wext[(size_t)(n0 + r) * KE + k0 + c];
            }
            __syncthreads();
            for (int kk = 0; kk < 32; ++kk) {
                double a0 = As[ty*4][kk], a1 = As[ty*4+1][kk], a2 = As[ty*4+2][kk], a3 = As[ty*4+3][kk];
                double w0 = Ws[tx*4][kk], w1 = Ws[tx*4+1][kk], w2 = Ws[tx*4+2][kk], w3 = Ws[tx*4+3][kk];
                acc[0][0] += a0*w0; acc[0][1] += a0*w1; acc[0][2] += a0*w2; acc[0][3] += a0*w3;
                acc[1][0] += a1*w0; acc[1][1] += a1*w1; acc[1][2] += a1*w2; acc[1][3] += a1*w3;
                acc[2][0] += a2*w0; acc[2][1] += a2*w1; acc[2][2] += a2*w2; acc[2][3] += a2*w3;
                acc[3][0] += a3*w0; acc[3][1] += a3*w1; acc[3][2] += a3*w2; acc[3][3] += a3*w3;
            }
            __syncthreads();
        }
#pragma unroll
        for (int i = 0; i < 4; ++i)
#pragma unroll
            for (int j = 0; j < 4; ++j)
                g_Pre[(size_t)(m0 + ty*4 + i) * NC + (n0 + tx*4 + j)] = (float)acc[i][j];
        __syncthreads();
    }
}

// ---------------- synthetic hx for step-GEMM probe ----------------
__global__ void synth_hx() {
    int i = blockIdx.x * 256 + threadIdx.x;
    if (i >= NB * ND) return;
    unsigned h = (unsigned)i * 2654435761u;
    float v = (float)((h >> 8) & 0xFFFFu) / 65536.0f - 0.5f;
    g_hx[i] = (double)v;
    u16 b0, b1, b2; decomp3(v, b0, b1, b2);
    g_hxb[i] = b0; g_hxb[PSH + i] = b1; g_hxb[2 * PSH + i] = b2;
}

// ---------------- per-step GEMM (bf16x3 MFMA | f64 vector): gbuf = hx @ Wstep^T + Pre[:,t,:] ----------------
__global__ __launch_bounds__(256) void step_gemm(int t, int probe) {
    __shared__ __align__(16) unsigned char shm[27648];
    int tid = threadIdx.x;
    int m0 = blockIdx.x * 32, n0 = blockIdx.y * 64;
    int use_mfma = g_ok && (probe || !g_badstep);
    if (use_mfma) {
        u16* usA = (u16*)shm;            // [3][32][48]
        u16* usB = usA + 4608;           // [3][64][48]
        int lane = tid & 63, wave = tid >> 6;
        int wm = (wave & 1) * 16, wn = (wave >> 1) * 32;
        int lr = lane & 15, lk = lane >> 4;
        f4v z = {0.f,0.f,0.f,0.f};
        f4v aP0=z, aP1=z, aC0=z, aC1=z;
        for (int k0 = 0; k0 < ND; k0 += 32) {
            for (int i = tid; i < 1152; i += 256) {
                if (i < 384) {
                    int p = i >> 7, rem = i & 127, r = rem >> 2, sg = rem & 3;
                    *(uint4*)(void*)(usA + p*1536 + r*48 + sg*8) =
                        *(const uint4*)(const void*)(g_hxb + (size_t)p*PSH + (size_t)(m0+r)*ND + k0 + sg*8);
                } else {
                    int j = i - 384;
                    int p = j >> 8, rem = j & 255, r = rem >> 2, sg = rem & 3;
                    *(uint4*)(void*)(usB + p*3072 + r*48 + sg*8) =
                        *(const uint4*)(const void*)(g_Wstepb + (size_t)p*PSWS + (size_t)(n0+r)*ND + k0 + sg*8);
                }
            }
            __syncthreads();
            const u16* pa = usA + (wm + lr) * 48 + 8 * lk;
            const u16* pb = usB + (wn + lr) * 48 + 8 * lk;
            s8v a0 = *(const s8v*)(const void*)(pa);
            s8v a1 = *(const s8v*)(const void*)(pa + 1536);
            s8v a2 = *(const s8v*)(const void*)(pa + 3072);
            s8v b0_0 = *(const s8v*)(const void*)(pb);
            s8v b0_1 = *(const s8v*)(const void*)(pb + 768);
            s8v b1_0 = *(const s8v*)(const void*)(pb + 3072);
            s8v b1_1 = *(const s8v*)(const void*)(pb + 3840);
            s8v b2_0 = *(const s8v*)(const void*)(pb + 6144);
            s8v b2_1 = *(const s8v*)(const void*)(pb + 6912);
            STEP6(aP0, aC0, a0, a1, a2, b0_0, b1_0, b2_0)
            STEP6(aP1, aC1, a0, a1, a2, b0_1, b1_1, b2_1)
            __syncthreads();
        }
        int rb = m0 + wm + 4 * lk, cb0 = n0 + wn + lr, cb1 = cb0 + 16;
#pragma unroll
        for (int r = 0; r < 4; ++r) {
            g_gbuf[(size_t)(rb + r) * NC + cb0] = (double)aP0[r] + (double)aC0[r]
                + (double)g_Pre[((size_t)(rb + r) * NS + t) * NC + cb0];
            g_gbuf[(size_t)(rb + r) * NC + cb1] = (double)aP1[r] + (double)aC1[r]
                + (double)g_Pre[((size_t)(rb + r) * NS + t) * NC + cb1];
        }
    } else {
        double* Asd = (double*)shm;          // [32][33]
        double* Wsd = Asd + 32 * 33;         // [64][33]
        int tx = tid & 15, ty = tid >> 4;
        double acc[2][4] = {};
        for (int k0 = 0; k0 < ND; k0 += 32) {
            for (int i = tid; i < 1024; i += 256) {
                int r = i >> 5, c = i & 31;
                Asd[r * 33 + c] = g_hx[(size_t)(m0 + r) * ND + k0 + c];
            }
            for (int i = tid; i < 2048; i += 256) {
                int r = i >> 5, c = i & 31;
                Wsd[r * 33 + c] = (double)g_Wstep[(size_t)(n0 + r) * ND + k0 + c];
            }
            __syncthreads();
            for (int kk = 0; kk < 32; ++kk) {
                double a0 = Asd[(ty*2)*33+kk], a1 = Asd[(ty*2+1)*33+kk];
                double w0 = Wsd[(tx*4)*33+kk], w1 = Wsd[(tx*4+1)*33+kk], w2 = Wsd[(tx*4+2)*33+kk], w3 = Wsd[(tx*4+3)*33+kk];
                acc[0][0] += a0*w0; acc[0][1] += a0*w1; acc[0][2] += a0*w2; acc[0][3] += a0*w3;
                acc[1][0] += a1*w0; acc[1][1] += a1*w1; acc[1][2] += a1*w2; acc[1][3] += a1*w3;
            }
            __syncthreads();
        }
#pragma unroll
        for (int i = 0; i < 2; ++i)
#pragma unroll
            for (int j = 0; j < 4; ++j) {
                int m = m0 + ty*2 + i, n = n0 + tx*4 + j;
                g_gbuf[(size_t)m * NC + n] = acc[i][j] + (double)g_Pre[((size_t)m * NS + t) * NC + n];
            }
    }
}

// ---------------- verify step-GEMM on synthetic state (t=0) ----------------
__global__ void verify_step() {
    int s = blockIdx.x * 256 + threadIdx.x;    // 2048 samples
    unsigned m = ((unsigned)s * 2654435761u) & 127u;
    unsigned n = ((unsigned)s * 40503u + 7u) % 2560u;
    double dot = 0.0;
    const double* hr = g_hx + (size_t)m * ND;
    const float*  wr = g_Wstep + (size_t)n * ND;
    for (int c = 0; c < ND; ++c) dot += hr[c] * (double)wr[c];
    dot += (double)g_Pre[((size_t)m * NS + 0) * NC + n];
    double got = g_gbuf[(size_t)m * NC + n];
    if (fabs(got - dot) > 1e-4 * (1.0 + fabs(dot))) atomicOr(&g_badstep, 1);
}

// ---------------- per-step elementwise (also maintains bf16x3 hx planes) ----------------
__global__ __launch_bounds__(256) void step_update(
    const float* __restrict__ W2, const float* __restrict__ b2,
    const int* __restrict__ lengths, int t) {
    int b = blockIdx.x, tid = threadIdx.x;
    const double* gb = g_gbuf + (size_t)b * NC;
    __shared__ double red[256][2];
    __shared__ double skipsh[2];
    double p0 = 0.0, p1 = 0.0;
    for (int j = tid; j < ND; j += 256) {
        double h = gb[2048 + j];
        h = h > 0.0 ? h : 0.0;
        p0 += h * (double)W2[j];
        p1 += h * (double)W2[ND + j];
    }
    red[tid][0] = p0; red[tid][1] = p1;
    __syncthreads();
    for (int s = 128; s > 0; s >>= 1) {
        if (tid < s) { red[tid][0] += red[tid + s][0]; red[tid][1] += red[tid + s][1]; }
        __syncthreads();
    }
    if (tid == 0) {
        double l0 = red[0][0] + (double)b2[0], l1 = red[0][1] + (double)b2[1];
        double mx = fmax(l0, l1);
        double sh0 = l0 - mx, sh1 = l1 - mx;
        double lsum = log(exp(sh0) + exp(sh1));
        double y0 = (sh0 - lsum) - g_gum[(size_t)t * (NB * 2) + b * 2 + 0];
        double y1 = (sh1 - lsum) - g_gum[(size_t)t * (NB * 2) + b * 2 + 1];
        double xx0 = y0 / 1e-5, xx1 = y1 / 1e-5;
        double mm = fmax(xx0, xx1);
        double e0 = exp(xx0 - mm), e1 = exp(xx1 - mm);
        double inv = 1.0 / (e0 + e1);
        skipsh[0] = e0 * inv; skipsh[1] = e1 * inv;
    }
    __syncthreads();
    double s0 = skipsh[0], s1 = skipsh[1];
    bool isFinal = (t == lengths[b] - 1);
    for (int j = tid; j < ND; j += 256) {
        double gi = gb[j], gf = gb[ND + j], gg = gb[2*ND + j], go = gb[3*ND + j];
        size_t ix = (size_t)b * ND + j;
        double cn = sigd(gf) * g_c[ix] + sigd(gi) * tanh(gg);
        double shx = sigd(go) * tanh(cn);
        double hn = g_hx[ix] * s1 + shx * s0;
        g_c[ix] = cn;
        g_hx[ix] = hn;
        u16 b0, b1, b2x; decomp3((float)hn, b0, b1, b2x);
        g_hxb[ix] = b0; g_hxb[PSH + ix] = b1; g_hxb[2 * PSH + ix] = b2x;
        if (isFinal) g_final[ix] = hn;
    }
}

// ---------------- final projection ----------------
__global__ __launch_bounds__(256) void final_out(const float* __restrict__ Wo,
                                                 const float* __restrict__ bo,
                                                 float* __restrict__ out) {
    int tid = threadIdx.x;
    int b = tid >> 1, k = tid & 1;
    double acc = 0.0;
    const double* f = g_final + (size_t)b * ND;
    const float* w = Wo + (size_t)k * ND;
    for (int d = 0; d < ND; ++d) acc += f[d] * (double)w[d];
    out[b * 2 + k] = (float)(acc + (double)bo[k]);
}

// ---------------- host launcher ----------------
extern "C" void kernel_launch(void* const* d_in, const int* in_sizes, int n_in,
                              void* d_out, int out_size, void* d_ws, size_t ws_size,
                              hipStream_t stream) {
    (void)in_sizes; (void)n_in; (void)d_ws; (void)ws_size; (void)out_size;
    const int*   seqs    = (const int*)d_in[0];
    const int*   lengths = (const int*)d_in[2];
    const float* emb     = (const float*)d_in[5];
    const float* revWih  = (const float*)d_in[6];
    const float* revWhh  = (const float*)d_in[7];
    const float* convw   = (const float*)d_in[8];
    const float* W1      = (const float*)d_in[9];
    const float* b1      = (const float*)d_in[10];
    const float* W2      = (const float*)d_in[11];
    const float* b2      = (const float*)d_in[12];
    const float* cWih    = (const float*)d_in[13];
    const float* cWhh    = (const float*)d_in[14];
    const float* Wo      = (const float*)d_in[15];
    const float* bo      = (const float*)d_in[16];
    float* out = (float*)d_out;

    double *A_p = nullptr, *Ap_p = nullptr;
    hipGetSymbolAddress((void**)&A_p,  HIP_SYMBOL(g_A));
    hipGetSymbolAddress((void**)&Ap_p, HIP_SYMBOL(g_Aproj));

    probe_bf16<<<1, 64, 0, stream>>>();
    build_w<<<NC, 256, 0, stream>>>(cWih, cWhh, W1, b1);
    gumbel_init<<<256, 256, 0, stream>>>();
    embed_sum<<<NBS, 128, 0, stream>>>(seqs, emb);

    gemm_f64<<<dim3(NBS / 64, 1), 256, 0, stream>>>(A_p, KE, revWih, ND, Ap_p, 40,
                                                    NBS, 40, ND);
    rev_lstm<<<NB, 64, 0, stream>>>(revWhh);
    conv_relu<<<dim3(NB, NS / 8), 256, 0, stream>>>(convw);
    decomp_A<<<4096, 256, 0, stream>>>();

    big_gemm<<<dim3(NC / 64, NBS / 64), 256, 0, stream>>>();
    verify_pre<<<32, 256, 0, stream>>>();
    big_fix<<<2048, 256, 0, stream>>>();

    // step-GEMM probe on synthetic state, then zero real state
    synth_hx<<<256, 256, 0, stream>>>();
    step_gemm<<<dim3(4, 40), 256, 0, stream>>>(0, 1);
    verify_step<<<8, 256, 0, stream>>>();
    init_state<<<256, 256, 0, stream>>>();

    for (int t = 0; t < NS; ++t) {
        step_gemm<<<dim3(4, 40), 256, 0, stream>>>(t, 0);
        step_update<<<NB, 256, 0, stream>>>(W2, b2, lengths, t);
    }
    final_out<<<1, 256, 0, stream>>>(Wo, bo, out);
}